// Round 6
// baseline (636.355 us; speedup 1.0000x reference)
//
#include <hip/hip_runtime.h>
#include <math.h>

typedef unsigned short u16;
typedef __bf16 bf16x8_t __attribute__((ext_vector_type(8)));
typedef float f32x4_t __attribute__((ext_vector_type(4)));

#define B_  2
#define S_  2048
#define D_  2048
#define H_  16
#define G_  4
#define DH_ 128

#define NEG_SENTINEL (-3.0e38f)
// 1/sqrt(128) * log2(e): folded into q at rope time so softmax uses exp2 directly
#define Q_SCALE (0.08838834764831843f * 1.4426950408889634f)

__device__ __forceinline__ float b2f(u16 u) {
    union { unsigned int i; float f; } v; v.i = ((unsigned int)u) << 16; return v.f;
}
__device__ __forceinline__ u16 f2b(float f) {
    union { float f; unsigned int i; } v; v.f = f;
    unsigned int r = v.i + 0x7fffu + ((v.i >> 16) & 1u);  // RNE
    return (u16)(r >> 16);
}
__device__ __forceinline__ void stc(u16* p, float v)   { *p = f2b(v); }
__device__ __forceinline__ void stc(float* p, float v) { *p = v; }

// ---------------------------------------------------------------------------
// Cast f32 -> bf16, 8 elems/thread.
// ---------------------------------------------------------------------------
__global__ __launch_bounds__(256) void cast_x(
    const float* __restrict__ in, u16* __restrict__ out) {
    int i = (blockIdx.x * 256 + threadIdx.x) * 8;
    float4 a = *(const float4*)(in + i);
    float4 b = *(const float4*)(in + i + 4);
    u16 o[8] = {f2b(a.x), f2b(a.y), f2b(a.z), f2b(a.w),
                f2b(b.x), f2b(b.y), f2b(b.z), f2b(b.w)};
    *(uint4*)(out + i) = *(uint4*)o;
}

// ---------------------------------------------------------------------------
// Transpose + cast: in f32 [R][C] -> out bf16 [C][R]. grid=(C/32, R/32)
// ---------------------------------------------------------------------------
__global__ __launch_bounds__(256) void transpose_f32_bf16(
    const float* __restrict__ in, u16* __restrict__ out, int R, int C) {
    __shared__ u16 t[32][33];
    const int c0 = blockIdx.x * 32, r0 = blockIdx.y * 32;
    const int j = threadIdx.x & 31, i = threadIdx.x >> 5;  // i in 0..7
#pragma unroll
    for (int p = 0; p < 4; ++p)
        t[i + 8 * p][j] = f2b(in[(size_t)(r0 + i + 8 * p) * C + c0 + j]);
    __syncthreads();
#pragma unroll
    for (int p = 0; p < 4; ++p)
        out[(size_t)(c0 + i + 8 * p) * R + r0 + j] = t[j][i + 8 * p];
}

// ---------------------------------------------------------------------------
// NT GEMM: C[M][N] = A[M][K] * BT[N][K]^T (bf16 in, OT out, f32 acc)
// block = 256 (4 waves), tile 128x128, BK=64. grid=(N/128, M/128)
// ---------------------------------------------------------------------------
template <typename OT>
__global__ __launch_bounds__(256) void gemm_nt(
    const u16* __restrict__ A, const u16* __restrict__ BT, OT* __restrict__ C,
    int M, int N, int K) {
    __shared__ __align__(16) u16 As[128 * 72];
    __shared__ __align__(16) u16 Bs[128 * 72];
    const int tid  = threadIdx.x;
    const int lane = tid & 63;
    const int wave = tid >> 6;
    const int wm = wave >> 1, wn = wave & 1;
    const int quad = lane >> 4, l16 = lane & 15;
    const int m0 = blockIdx.y * 128, n0 = blockIdx.x * 128;

    f32x4_t acc[4][4] = {};

    for (int k0 = 0; k0 < K; k0 += 64) {
#pragma unroll
        for (int c = tid; c < 1024; c += 256) {
            int row = c >> 3, cc = (c & 7) << 3;
            *(uint4*)(&As[row * 72 + cc]) =
                *(const uint4*)(A + (size_t)(m0 + row) * K + k0 + cc);
            *(uint4*)(&Bs[row * 72 + cc]) =
                *(const uint4*)(BT + (size_t)(n0 + row) * K + k0 + cc);
        }
        __syncthreads();
#pragma unroll
        for (int ks = 0; ks < 2; ++ks) {
            const int koff = ks * 32 + quad * 8;
            bf16x8_t a[4], b[4];
#pragma unroll
            for (int mt = 0; mt < 4; ++mt)
                a[mt] = *(const bf16x8_t*)(&As[(wm * 64 + mt * 16 + l16) * 72 + koff]);
#pragma unroll
            for (int nt = 0; nt < 4; ++nt)
                b[nt] = *(const bf16x8_t*)(&Bs[(wn * 64 + nt * 16 + l16) * 72 + koff]);
#pragma unroll
            for (int mt = 0; mt < 4; ++mt)
#pragma unroll
                for (int nt = 0; nt < 4; ++nt)
                    acc[mt][nt] = __builtin_amdgcn_mfma_f32_16x16x32_bf16(
                        a[mt], b[nt], acc[mt][nt], 0, 0, 0);
        }
        __syncthreads();
    }
#pragma unroll
    for (int mt = 0; mt < 4; ++mt)
#pragma unroll
        for (int nt = 0; nt < 4; ++nt)
#pragma unroll
            for (int r = 0; r < 4; ++r) {
                int m = m0 + wm * 64 + mt * 16 + quad * 4 + r;
                int n = n0 + wn * 64 + nt * 16 + l16;
                stc(C + (size_t)m * N + n, acc[mt][nt][r]);
            }
}

// ---------------------------------------------------------------------------
// RoPE on q in-place (bf16), folding Q_SCALE (softmax scale * log2e) into q.
// q layout [B][S][H][DH].
// ---------------------------------------------------------------------------
__global__ __launch_bounds__(256) void rope_q(u16* q) {
    int idx = blockIdx.x * 256 + threadIdx.x;
    int d = idx & 63;
    int t = idx >> 6;
    int h = t & 15; t >>= 4;
    int s = t & 2047;
    int b = t >> 11;
    size_t base = ((size_t)(b * S_ + s) * H_ + h) * DH_;
    float x1 = b2f(q[base + d]), x2 = b2f(q[base + d + 64]);
    float inv = exp2f(-(float)d * (13.287712379549449f / 64.f));  // 10000^(-d/64)
    float ang = (float)s * inv, sn, cs;
    sincosf(ang, &sn, &cs);
    q[base + d]      = f2b((x1 * cs - x2 * sn) * Q_SCALE);
    q[base + d + 64] = f2b((x2 * cs + x1 * sn) * Q_SCALE);
}

// ---------------------------------------------------------------------------
// RoPE on k: kvraw bf16 [B*S][1024] (cols 0..511 = k) ->
//   kc f32 [B][G][S][DH] (output) and kb bf16 same layout (for MFMA)
// ---------------------------------------------------------------------------
__global__ __launch_bounds__(256) void k_prep(
    const u16* __restrict__ kvraw, float* __restrict__ kc, u16* __restrict__ kb) {
    int idx = blockIdx.x * 256 + threadIdx.x;
    int d = idx & 63;
    int t = idx >> 6;
    int g = t & 3; t >>= 2;
    int s = t & 2047;
    int b = t >> 11;
    const u16* src = kvraw + (size_t)(b * S_ + s) * 1024 + g * DH_;
    float x1 = b2f(src[d]), x2 = b2f(src[d + 64]);
    float inv = exp2f(-(float)d * (13.287712379549449f / 64.f));
    float ang = (float)s * inv, sn, cs;
    sincosf(ang, &sn, &cs);
    float r1 = x1 * cs - x2 * sn;
    float r2 = x2 * cs + x1 * sn;
    size_t o = ((size_t)(b * G_ + g) * S_ + s) * DH_;
    kc[o + d]      = r1;
    kc[o + d + 64] = r2;
    kb[o + d]      = f2b(r1);
    kb[o + d + 64] = f2b(r2);
}

// ---------------------------------------------------------------------------
// v: emit v_cache f32 [B][G][S][DH] and v^T bf16 [B][G][DH][S]
// grid=(S/32, DH/32, B*G), block=256
// ---------------------------------------------------------------------------
__global__ __launch_bounds__(256) void v_prep(
    const u16* __restrict__ kvraw, float* __restrict__ vc, u16* __restrict__ vt) {
    __shared__ u16 t[32][33];
    const int s0 = blockIdx.x * 32, d0 = blockIdx.y * 32;
    const int bg = blockIdx.z, b = bg >> 2, g = bg & 3;
    const int j = threadIdx.x & 31, i = threadIdx.x >> 5;
#pragma unroll
    for (int p = 0; p < 4; ++p) {
        int s = s0 + i + 8 * p;
        u16 v = kvraw[(size_t)(b * S_ + s) * 1024 + 512 + g * DH_ + d0 + j];
        t[i + 8 * p][j] = v;
        vc[((size_t)bg * S_ + s) * DH_ + d0 + j] = b2f(v);
    }
    __syncthreads();
#pragma unroll
    for (int p = 0; p < 4; ++p)
        vt[((size_t)bg * DH_ + d0 + i + 8 * p) * S_ + s0 + j] = t[j][i + 8 * p];
}

// ---------------------------------------------------------------------------
// Flash attention v4: LDS-free, barrier-free, S^T-form.
// grid=(16,16,2), block=256 (4 independent waves). Each wave owns one 32-row
// q-tile (64 tiles per (b,h)) and free-runs its causal kv loop.
//
// S^T = K*Q^T: mfma(A=K-frag, B=Q-frag) puts q-rows on the LANE axis ->
// per-lane softmax stats, 2-step cross-quad reductions.
// P^T for PV is built by 32 quad-level __shfl's (no LDS roundtrip):
//   dest lane (qd,l) frag j=0..7 needs S^T regs of lanes ((2qd)&3,l) and
//   ((2qd+1)&3,l), from pk[2ks + (qd>>1)].
// O^T = V^T * P^T: V-fragments straight from global (64B-coalesced).
// XCD heuristic: (b,g) = linear&7 so each XCD streams one K/V set.
// ---------------------------------------------------------------------------
__global__ __launch_bounds__(256, 2) void flash_attn(
    const u16* __restrict__ q, const u16* __restrict__ kb,
    const u16* __restrict__ vt, u16* __restrict__ ctx) {
    const int tid  = threadIdx.x;
    const int lane = tid & 63;
    const int wave = tid >> 6;
    const int quad = lane >> 4, l16 = lane & 15;

    const int linear = blockIdx.x + 16 * (blockIdx.y + 16 * blockIdx.z);
    const int slot = linear & 7;            // -> (b,g), one per XCD slot
    const int b = slot >> 2, g = slot & 3;
    const int rest = linear >> 3;           // 0..63
    const int h = g * 4 + (rest >> 4);      // 0..15
    const int tile = (rest & 15) * 4 + wave;  // 0..63, 32 q-rows each

    const u16* Kp = kb + (size_t)(b * G_ + g) * S_ * DH_;
    const u16* Vt = vt + (size_t)(b * G_ + g) * DH_ * S_;
    const int q0w = tile * 32;

    // Q fragments (B-operand): lane holds Q[q0w+ntq*16+l16][ks*32+quad*8+j]
    bf16x8_t qf[2][4];
#pragma unroll
    for (int ntq = 0; ntq < 2; ++ntq)
#pragma unroll
        for (int ks = 0; ks < 4; ++ks)
            qf[ntq][ks] = *(const bf16x8_t*)(
                q + ((size_t)(b * S_ + q0w + ntq * 16 + l16) * H_ + h) * DH_
                  + ks * 32 + quad * 8);

    f32x4_t o[8][2] = {};                 // O^T[d-tile][q-ntile]
    float m_i[2] = {NEG_SENTINEL, NEG_SENTINEL};
    float l_i[2] = {0.f, 0.f};

    const int srcA = ((2 * quad) & 3) * 16 + l16;
    const int srcB = ((2 * quad + 1) & 3) * 16 + l16;
    const bool hi = (quad >> 1) != 0;

    const int kvend = q0w + 32;
    for (int kv0 = 0; kv0 < kvend; kv0 += 64) {
        // ---- S^T = K Q^T : s[mkv][ntq], row=kv (quad*4+r), col=q_row (l16)
        f32x4_t s[4][2] = {};
#pragma unroll
        for (int ks = 0; ks < 4; ++ks) {
            bf16x8_t kf[4];
#pragma unroll
            for (int mkv = 0; mkv < 4; ++mkv)
                kf[mkv] = *(const bf16x8_t*)(
                    Kp + (size_t)(kv0 + mkv * 16 + l16) * DH_ + ks * 32 + quad * 8);
#pragma unroll
            for (int mkv = 0; mkv < 4; ++mkv)
#pragma unroll
                for (int ntq = 0; ntq < 2; ++ntq)
                    s[mkv][ntq] = __builtin_amdgcn_mfma_f32_16x16x32_bf16(
                        kf[mkv], qf[ntq][ks], s[mkv][ntq], 0, 0, 0);
        }
        // ---- causal mask (diagonal vicinity only)
        if (kv0 + 63 > q0w) {
#pragma unroll
            for (int mkv = 0; mkv < 4; ++mkv)
#pragma unroll
                for (int ntq = 0; ntq < 2; ++ntq)
#pragma unroll
                    for (int r = 0; r < 4; ++r) {
                        int kv_abs = kv0 + mkv * 16 + quad * 4 + r;
                        int q_abs  = q0w + ntq * 16 + l16;
                        if (kv_abs > q_abs) s[mkv][ntq][r] = NEG_SENTINEL;
                    }
        }
        // ---- per-lane online softmax + bf16 pack
        unsigned int pk[4][2][2];
#pragma unroll
        for (int ntq = 0; ntq < 2; ++ntq) {
            float mx = s[0][ntq][0];
#pragma unroll
            for (int mkv = 0; mkv < 4; ++mkv)
#pragma unroll
                for (int r = 0; r < 4; ++r) mx = fmaxf(mx, s[mkv][ntq][r]);
            mx = fmaxf(mx, __shfl_xor(mx, 16));
            mx = fmaxf(mx, __shfl_xor(mx, 32));
            float mnew  = fmaxf(m_i[ntq], mx);
            float alpha = exp2f(m_i[ntq] - mnew);
            m_i[ntq] = mnew;
            float rs = 0.f;
#pragma unroll
            for (int mkv = 0; mkv < 4; ++mkv)
#pragma unroll
                for (int r = 0; r < 4; ++r) {
                    float p = exp2f(s[mkv][ntq][r] - mnew);
                    s[mkv][ntq][r] = p;
                    rs += p;
                }
            rs += __shfl_xor(rs, 16);
            rs += __shfl_xor(rs, 32);
            l_i[ntq] = l_i[ntq] * alpha + rs;
#pragma unroll
            for (int nt = 0; nt < 8; ++nt) o[nt][ntq] *= alpha;
#pragma unroll
            for (int mkv = 0; mkv < 4; ++mkv) {
                pk[mkv][ntq][0] = (unsigned int)f2b(s[mkv][ntq][0]) |
                                  ((unsigned int)f2b(s[mkv][ntq][1]) << 16);
                pk[mkv][ntq][1] = (unsigned int)f2b(s[mkv][ntq][2]) |
                                  ((unsigned int)f2b(s[mkv][ntq][3]) << 16);
            }
        }
        // ---- O^T += V^T P^T  (P^T B-frags via quad shuffles)
#pragma unroll
        for (int ks = 0; ks < 2; ++ks) {
            bf16x8_t pf[2];
#pragma unroll
            for (int ntq = 0; ntq < 2; ++ntq) {
                union { unsigned int u[4]; bf16x8_t v; } pu;
                int a0 = __shfl((int)pk[2 * ks][ntq][0], srcA);
                int b0 = __shfl((int)pk[2 * ks + 1][ntq][0], srcA);
                int a1 = __shfl((int)pk[2 * ks][ntq][1], srcA);
                int b1 = __shfl((int)pk[2 * ks + 1][ntq][1], srcA);
                int a2 = __shfl((int)pk[2 * ks][ntq][0], srcB);
                int b2 = __shfl((int)pk[2 * ks + 1][ntq][0], srcB);
                int a3 = __shfl((int)pk[2 * ks][ntq][1], srcB);
                int b3 = __shfl((int)pk[2 * ks + 1][ntq][1], srcB);
                pu.u[0] = (unsigned int)(hi ? b0 : a0);
                pu.u[1] = (unsigned int)(hi ? b1 : a1);
                pu.u[2] = (unsigned int)(hi ? b2 : a2);
                pu.u[3] = (unsigned int)(hi ? b3 : a3);
                pf[ntq] = pu.v;
            }
#pragma unroll
            for (int nt = 0; nt < 8; ++nt) {
                bf16x8_t vf = *(const bf16x8_t*)(
                    Vt + (size_t)(nt * 16 + l16) * S_ + kv0 + ks * 32 + quad * 8);
#pragma unroll
                for (int ntq = 0; ntq < 2; ++ntq)
                    o[nt][ntq] = __builtin_amdgcn_mfma_f32_16x16x32_bf16(
                        vf, pf[ntq], o[nt][ntq], 0, 0, 0);
            }
        }
    }
    // ---- epilogue: lane holds O^T[d=nt*16+quad*4+r][q_row=ntq*16+l16]
#pragma unroll
    for (int ntq = 0; ntq < 2; ++ntq) {
        float inv = 1.f / l_i[ntq];
        size_t base = ((size_t)(b * S_ + q0w + ntq * 16 + l16) * H_ + h) * DH_;
#pragma unroll
        for (int nt = 0; nt < 8; ++nt) {
            u16 pkd[4];
#pragma unroll
            for (int r = 0; r < 4; ++r) pkd[r] = f2b(o[nt][ntq][r] * inv);
            *(uint2*)(ctx + base + nt * 16 + quad * 4) = *(uint2*)pkd;
        }
    }
}

// ---------------------------------------------------------------------------
extern "C" void kernel_launch(void* const* d_in, const int* in_sizes, int n_in,
                              void* d_out, int out_size, void* d_ws, size_t ws_size,
                              hipStream_t stream) {
    const float* x  = (const float*)d_in[0];
    const float* Wq = (const float*)d_in[1];
    const float* Wk = (const float*)d_in[2];
    const float* Wv = (const float*)d_in[3];
    const float* Wo = (const float*)d_in[4];
    // d_in[5] = mask (unused; causal computed analytically)

    float* out    = (float*)d_out;                           // [B][S][H*DH]  8,388,608 f32
    float* kc_out = out + (size_t)B_ * S_ * H_ * DH_;        // [B][G][S][DH] 2,097,152 f32
    float* vc_out = kc_out + (size_t)B_ * G_ * S_ * DH_;     // [B][G][S][DH] 2,097,152 f32

    // Borrow `out` f32 region (= 16M u16) as early scratch; both buffers are
    // dead before the final gemm writes `out` (single stream, serialized).
    u16* outw = (u16*)d_out;
    u16* xb   = outw;             // 8M u16, live phases 1-2 (x cast to bf16)
    u16* qraw = outw + 8388608;   // 8M u16, live phases 2-4

    // Workspace: 16M u16 = 32 MiB, phase-safe overlays
    u16* ws    = (u16*)d_ws;
    u16* WqT   = ws;              // 4M, phases 1-2
    u16* WoT   = ws;              // 4M, phases 3-5 (transposed after q-gemm)
    u16* WkvT  = ws + 4194304;    // 2M, phases 1-2
    u16* kb    = ws + 4194304;    // 2M, phases 3-4
    u16* vt    = ws + 6291456;    // 2M, phases 3-4
    u16* kvraw = ws + 8388608;    // 4M, phases 2-3
    u16* ctx   = ws + 8388608;    // 8M, phases 4-5

    dim3 blk(256);
    // phase 1: casts + W transposes
    cast_x<<<dim3(4096), blk, 0, stream>>>(x, xb);
    transpose_f32_bf16<<<dim3(64, 64), blk, 0, stream>>>(Wq, WqT, 2048, 2048);
    transpose_f32_bf16<<<dim3(16, 64), blk, 0, stream>>>(Wk, WkvT, 2048, 512);
    transpose_f32_bf16<<<dim3(16, 64), blk, 0, stream>>>(Wv, WkvT + (size_t)512 * 2048, 2048, 512);

    // phase 2: projections
    gemm_nt<u16><<<dim3(16, 32), blk, 0, stream>>>(xb, WqT, qraw, 4096, 2048, 2048);
    gemm_nt<u16><<<dim3(8, 32),  blk, 0, stream>>>(xb, WkvT, kvraw, 4096, 1024, 2048);

    // phase 3: RoPE + cache outputs (+ Wo transpose into WqT's slot)
    transpose_f32_bf16<<<dim3(64, 64), blk, 0, stream>>>(Wo, WoT, 2048, 2048);
    rope_q<<<dim3(16384), blk, 0, stream>>>(qraw);
    k_prep<<<dim3(4096),  blk, 0, stream>>>(kvraw, kc_out, kb);
    v_prep<<<dim3(64, 4, 8), blk, 0, stream>>>(kvraw, vc_out, vt);

    // phase 4: attention (LDS-free, barrier-free, S^T-form)
    flash_attn<<<dim3(16, 16, 2), blk, 0, stream>>>(qraw, kb, vt, ctx);

    // phase 5: output projection (f32 out)
    gemm_nt<float><<<dim3(16, 32), blk, 0, stream>>>(ctx, WoT, out, 4096, 2048, 2048);
}